// Round 4
// baseline (4614.062 us; speedup 1.0000x reference)
//
#include <hip/hip_runtime.h>

// ---------------- types / helpers ----------------
typedef unsigned short u16;
typedef unsigned int   u32;
typedef __bf16 bf16x8 __attribute__((ext_vector_type(8)));
typedef float  f32x4  __attribute__((ext_vector_type(4)));

__device__ __forceinline__ u16 f2bf(float f) {
    u32 u = __builtin_bit_cast(u32, f);
    u = u + 0x7fffu + ((u >> 16) & 1u);
    return (u16)(u >> 16);
}
__device__ __forceinline__ float bflo(u32 u) { return __builtin_bit_cast(float, u << 16); }
__device__ __forceinline__ float bfhi(u32 u) { return __builtin_bit_cast(float, u & 0xffff0000u); }
__device__ __forceinline__ u32 pack2(float x, float y) { return (u32)f2bf(x) | ((u32)f2bf(y) << 16); }

#define NN 100000
#define EE 400000
#define DP 320   // padded D (300 -> 320)
#define HP 640   // padded 2D (600 -> 640)

// ---------------- preprocessing ----------------
__global__ void count_deg(const int* __restrict__ ei, int* __restrict__ deg, int E) {
    int e = blockIdx.x * 256 + threadIdx.x;
    if (e < E) atomicAdd(&deg[ei[E + e]], 1);
}

__global__ void scan1(const int* __restrict__ deg, int* __restrict__ out, int* __restrict__ bsums, int n) {
    __shared__ int lds[1024];
    int t = threadIdx.x;
    int i = blockIdx.x * 1024 + t;
    int v = (i < n) ? deg[i] : 0;
    lds[t] = v;
    __syncthreads();
    for (int d = 1; d < 1024; d <<= 1) {
        int add = (t >= d) ? lds[t - d] : 0;
        __syncthreads();
        lds[t] += add;
        __syncthreads();
    }
    if (i < n) out[i] = lds[t] - v;   // exclusive
    if (t == 1023) bsums[blockIdx.x] = lds[t];
}

__global__ void scan2(int* __restrict__ bsums, int nb) {
    __shared__ int lds[128];
    int t = threadIdx.x;
    int v = (t < nb) ? bsums[t] : 0;
    lds[t] = v;
    __syncthreads();
    for (int d = 1; d < 128; d <<= 1) {
        int add = (t >= d) ? lds[t - d] : 0;
        __syncthreads();
        lds[t] += add;
        __syncthreads();
    }
    if (t < nb) bsums[t] = lds[t] - v;
}

__global__ void scan3(int* __restrict__ out, const int* __restrict__ bsums, int n, int etot) {
    int i = blockIdx.x * 1024 + threadIdx.x;
    if (i < n) out[i] += bsums[blockIdx.x];
    else if (i == n) out[i] = etot;
}

__global__ void fill_csr(const int* __restrict__ ei, const int* __restrict__ ea,
                         int* __restrict__ cursors, u32* __restrict__ vals, int E) {
    int e = blockIdx.x * 256 + threadIdx.x;
    if (e >= E) return;
    int dst = ei[E + e];
    int src = ei[e];
    u32 code = (u32)((ea[e*4] & 1) | ((ea[e*4+1] & 1) << 1) | ((ea[e*4+2] & 1) << 2) | ((ea[e*4+3] & 1) << 3));
    int pos = atomicAdd(&cursors[dst], 1);
    vals[pos] = ((u32)src << 4) | code;
}

// weights -> transposed padded bf16 (B^T layout for MFMA B-operand)
__global__ void conv_w1(const float* __restrict__ w, u16* __restrict__ wt) {
    // w: [5][300][600] -> wt: [5][640][320]  (wt[l][n][k] = w[l][k][n])
    int id = blockIdx.x * 256 + threadIdx.x;
    if (id >= 5 * HP * DP) return;
    int l = id / (HP * DP);
    int rem = id - l * (HP * DP);
    int n = rem / DP;
    int k = rem - n * DP;
    u16 v = 0;
    if (n < 600 && k < 300) v = f2bf(w[((size_t)l * 300 + k) * 600 + n]);
    wt[id] = v;
}
__global__ void conv_w2(const float* __restrict__ w, u16* __restrict__ wt) {
    // w: [5][600][300] -> wt: [5][320][640]
    int id = blockIdx.x * 256 + threadIdx.x;
    if (id >= 5 * DP * HP) return;
    int l = id / (DP * HP);
    int rem = id - l * (DP * HP);
    int n = rem / HP;
    int k = rem - n * HP;
    u16 v = 0;
    if (n < 300 && k < 600) v = f2bf(w[((size_t)l * 600 + k) * 300 + n]);
    wt[id] = v;
}

// atom encoder -> y bf16 (layer-0 "post-BN" state is just the embedding sum)
__global__ void atom_enc(const int* __restrict__ x, const float* __restrict__ at, u16* __restrict__ y) {
    const int i = blockIdx.x;
    const int d = threadIdx.x; // 0..319
    __shared__ int xi[7];
    if (d < 7) xi[d] = x[i * 7 + d];
    __syncthreads();
    u16 v = 0;
    if (d < 300) {
        float s = 0.f;
        #pragma unroll
        for (int f = 0; f < 7; ++f) s += at[(f * 119 + xi[f]) * 300 + d];
        v = f2bf(s);
    }
    y[(size_t)i * DP + d] = v;
}

// per-layer bond embedding table: 16 codes + self-loop (index 16)
__global__ void bond_enc(const float* __restrict__ bt, float* __restrict__ emb) {
    const int c = blockIdx.x;  // 0..16
    const int d = threadIdx.x; // 0..319
    float s = 0.f;
    if (d < 300) {
        if (c < 16) {
            #pragma unroll
            for (int f = 0; f < 4; ++f) s += bt[(f * 6 + ((c >> f) & 1)) * 300 + d];
        } else {
            s = bt[4 * 300 + d];  // bond[0][4]
            #pragma unroll
            for (int f = 1; f < 4; ++f) s += bt[f * 6 * 300 + d];
        }
    }
    emb[c * DP + d] = s;
}

// stats -> BN (scale, shift)
__global__ void bn_ss(const float* __restrict__ stats, const float* __restrict__ gamma,
                      const float* __restrict__ beta, float* __restrict__ scale,
                      float* __restrict__ shift, int n) {
    int d = threadIdx.x;
    float sc = 0.f, sh = 0.f;
    if (d < 300) {
        float inv_n = 1.0f / (float)n;
        float mu = stats[d] * inv_n;
        float var = stats[DP + d] * inv_n - mu * mu;
        float inv = 1.0f / sqrtf(var + 1e-5f);
        sc = gamma[d] * inv;
        sh = beta[d] - mu * sc;
    }
    scale[d] = sc; shift[d] = sh;
}

// y[i][d] = bf16(relu(scale*h_raw + shift))   (pads: scale=shift=0, h pad=0 -> 0)
__global__ void bn_apply(const float* __restrict__ hraw, const float* __restrict__ scale,
                         const float* __restrict__ shift, u16* __restrict__ y) {
    const int i = blockIdx.x;
    const int d = threadIdx.x;
    float v = fmaf(scale[d], hraw[(size_t)i * DP + d], shift[d]);
    y[(size_t)i * DP + d] = f2bf(fmaxf(v, 0.f));
}

// ---------------- aggregation: one wave per node, batch-4 edge unroll ----------------
// agg[i] = y[i] + self_emb + sum_edges ( y[src] + emb16[code] )
__global__ void aggregate(const u16* __restrict__ y,
                          const float* __restrict__ emb,
                          const int* __restrict__ offs, const u32* __restrict__ vals,
                          u16* __restrict__ agg, const int n) {
    const int wid = (int)((blockIdx.x * (size_t)blockDim.x + threadIdx.x) >> 6);
    const int lane = threadIdx.x & 63;
    if (wid >= n) return;
    const int j0 = lane, j1 = lane + 64, j2 = lane + 128;
    const bool has2 = (lane < 32);

    float a0x = 0.f, a0y = 0.f, a1x = 0.f, a1y = 0.f, a2x = 0.f, a2y = 0.f;

    auto addrow = [&](u32 u0, u32 u1, u32 u2, const float* er) {
        float2 e0 = *(const float2*)(er + 2 * j0);
        float2 e1 = *(const float2*)(er + 2 * j1);
        a0x += bflo(u0) + e0.x;  a0y += bfhi(u0) + e0.y;
        a1x += bflo(u1) + e1.x;  a1y += bfhi(u1) + e1.y;
        if (has2) {
            float2 e2 = *(const float2*)(er + 2 * j2);
            a2x += bflo(u2) + e2.x;  a2y += bfhi(u2) + e2.y;
        }
    };

    {   // self loop
        const u32* r = (const u32*)y + (size_t)wid * (DP / 2);
        addrow(r[j0], r[j1], has2 ? r[j2] : 0u, emb + 16 * DP);
    }
    int e = offs[wid];
    const int t = offs[wid + 1];
    for (; e + 4 <= t; e += 4) {
        u32 v0 = vals[e], v1 = vals[e + 1], v2 = vals[e + 2], v3 = vals[e + 3];
        const u32* r0 = (const u32*)y + (size_t)(v0 >> 4) * (DP / 2);
        const u32* r1 = (const u32*)y + (size_t)(v1 >> 4) * (DP / 2);
        const u32* r2 = (const u32*)y + (size_t)(v2 >> 4) * (DP / 2);
        const u32* r3 = (const u32*)y + (size_t)(v3 >> 4) * (DP / 2);
        u32 x00 = r0[j0], x01 = r0[j1], x02 = has2 ? r0[j2] : 0u;
        u32 x10 = r1[j0], x11 = r1[j1], x12 = has2 ? r1[j2] : 0u;
        u32 x20 = r2[j0], x21 = r2[j1], x22 = has2 ? r2[j2] : 0u;
        u32 x30 = r3[j0], x31 = r3[j1], x32 = has2 ? r3[j2] : 0u;
        addrow(x00, x01, x02, emb + (v0 & 15u) * DP);
        addrow(x10, x11, x12, emb + (v1 & 15u) * DP);
        addrow(x20, x21, x22, emb + (v2 & 15u) * DP);
        addrow(x30, x31, x32, emb + (v3 & 15u) * DP);
    }
    for (; e < t; ++e) {
        u32 v = vals[e];
        const u32* r = (const u32*)y + (size_t)(v >> 4) * (DP / 2);
        addrow(r[j0], r[j1], has2 ? r[j2] : 0u, emb + (v & 15u) * DP);
    }

    u32* outp = (u32*)agg + (size_t)wid * (DP / 2);
    outp[j0] = pack2(a0x, a0y);
    outp[j1] = pack2(a1x, a1y);
    if (has2) outp[j2] = pack2(a2x, a2y);
}

// ---------------- fused MLP: h_raw = (relu(agg@W1+b1))@W2 + b2, + BN stats ----------------
// Block = 64 rows, 4 waves; each wave owns 16 rows x all 320 output cols.
// A-frags and W-frags load directly from global (W is L1/L2-resident).
// hid LDS slab is per-wave-private (intra-wave C-layout -> A-layout transpose):
// NO barriers in the main loop.
#define HSTR 40    // hid row stride (u16): 80 B, 16B-aligned, 2-way banks

__global__ __launch_bounds__(256, 3) void fused_mlp(
    const u16* __restrict__ A,      // agg [N][320] bf16
    const u16* __restrict__ W1t,    // [640][320] bf16 (W1^T)
    const u16* __restrict__ W2t,    // [320][640] bf16 (W2^T)
    const float* __restrict__ b1g,  // [600]
    const float* __restrict__ b2g,  // [300]
    float* __restrict__ H,          // h_raw [N][320] fp32
    float* __restrict__ st1, float* __restrict__ st2,
    const int M) {

    __shared__ __align__(16) u16 hid[64 * HSTR];   // 5.1 KB, per-wave-private slabs
    __shared__ float sst[2 * DP];                  // 2.56 KB block stats

    const int tid  = threadIdx.x;
    const int wid  = tid >> 6;
    const int lane = tid & 63;
    const int l15  = lane & 15;
    const int q    = lane >> 4;
    const int bm   = blockIdx.x * 64;

    // zero block stats (ordered before epilogue atomics by the barrier below)
    sst[tid] = 0.f; sst[tid + 256] = 0.f;
    if (tid < 128) sst[tid + 512] = 0.f;
    __syncthreads();

    // ---- A fragments: 16 rows x 320 k, direct from global ----
    const int row_a = bm + wid * 16 + l15;
    const bool rv = (row_a < M);
    const u16* arow = A + (size_t)row_a * DP + q * 8;
    bf16x8 afr[10];
    #pragma unroll
    for (int kt = 0; kt < 10; ++kt) {
        uint4 tv; tv.x = tv.y = tv.z = tv.w = 0;
        if (rv) tv = *(const uint4*)(arow + kt * 32);
        afr[kt] = __builtin_bit_cast(bf16x8, tv);
    }

    f32x4 acc2[20];
    #pragma unroll
    for (int nf = 0; nf < 20; ++nf) acc2[nf] = (f32x4){0.f, 0.f, 0.f, 0.f};

    const u16* w1l = W1t + (size_t)l15 * DP + q * 8;  // lane's W1 frag base
    const u16* w2l = W2t + (size_t)l15 * HP + q * 8;  // lane's W2 frag base
    u16* hw = &hid[(wid * 16) * HSTR];                // this wave's private slab

    for (int c = 0; c < 20; ++c) {
        // ---- GEMM1: 16 rows x 32 hidden cols ----
        f32x4 acc1[2] = {(f32x4){0.f,0.f,0.f,0.f}, (f32x4){0.f,0.f,0.f,0.f}};
        const u16* w1c = w1l + (size_t)(c * 32) * DP;
        #pragma unroll
        for (int kt = 0; kt < 10; ++kt) {
            bf16x8 wa = __builtin_bit_cast(bf16x8, *(const uint4*)(w1c + kt * 32));
            bf16x8 wb = __builtin_bit_cast(bf16x8, *(const uint4*)(w1c + (size_t)16 * DP + kt * 32));
            acc1[0] = __builtin_amdgcn_mfma_f32_16x16x32_bf16(afr[kt], wa, acc1[0], 0, 0, 0);
            acc1[1] = __builtin_amdgcn_mfma_f32_16x16x32_bf16(afr[kt], wb, acc1[1], 0, 0, 0);
        }
        // bias + relu -> private hid slab (C-layout: col=l15, row=q*4+r)
        #pragma unroll
        for (int h = 0; h < 2; ++h) {
            int gcol = c * 32 + h * 16 + l15;
            float bb = (gcol < 600) ? b1g[gcol] : 0.f;
            #pragma unroll
            for (int r = 0; r < 4; ++r) {
                float v = fmaxf(acc1[h][r] + bb, 0.f);
                hw[(q * 4 + r) * HSTR + h * 16 + l15] = f2bf(v);
            }
        }
        // ---- transpose readback: A-frag for GEMM2 (same wave, lgkmcnt only) ----
        bf16x8 a2 = __builtin_bit_cast(bf16x8, *(const uint4*)&hw[l15 * HSTR + q * 8]);
        // ---- GEMM2: accumulate 16 rows x 320 cols over this 32-k chunk ----
        const u16* w2c = w2l + c * 32;
        #pragma unroll
        for (int nf = 0; nf < 20; ++nf) {
            bf16x8 wf = __builtin_bit_cast(bf16x8, *(const uint4*)(w2c + (size_t)(nf * 16) * HP));
            acc2[nf] = __builtin_amdgcn_mfma_f32_16x16x32_bf16(a2, wf, acc2[nf], 0, 0, 0);
        }
    }

    // ---- epilogue: bias2, store fp32 raw h, block-level BN stats ----
    #pragma unroll
    for (int nf = 0; nf < 20; ++nf) {
        const int col = nf * 16 + l15;
        const float bb = (col < 300) ? b2g[col] : 0.f;
        float s1 = 0.f, s2 = 0.f;
        #pragma unroll
        for (int r = 0; r < 4; ++r) {
            const int row = bm + wid * 16 + q * 4 + r;
            if (row < M) {
                float v = acc2[nf][r] + bb;
                H[(size_t)row * DP + col] = v;
                s1 += v; s2 += v * v;
            }
        }
        s1 += __shfl_xor(s1, 16); s1 += __shfl_xor(s1, 32);
        s2 += __shfl_xor(s2, 16); s2 += __shfl_xor(s2, 32);
        if (q == 0) { atomicAdd(&sst[col], s1); atomicAdd(&sst[DP + col], s2); }
    }
    __syncthreads();
    for (int i = tid; i < 2 * DP; i += 256) {
        float v = sst[i];
        if (i < DP) atomicAdd(&st1[i], v);
        else        atomicAdd(&st2[i - DP], v);
    }
}

// final: d_out[i][d] = scale[d]*raw[i][d] + shift[d]  (no relu, fp32 in/out)
__global__ void finalize(const float* __restrict__ hraw, const float* __restrict__ scale,
                         const float* __restrict__ shift, float* __restrict__ out) {
    const int i = blockIdx.x;
    const int d = threadIdx.x;
    if (d < 300) {
        float x = hraw[(size_t)i * DP + d];
        out[(size_t)i * 300 + d] = fmaf(scale[d], x, shift[d]);
    }
}

// ---------------- launcher ----------------
extern "C" void kernel_launch(void* const* d_in, const int* in_sizes, int n_in,
                              void* d_out, int out_size, void* d_ws, size_t ws_size,
                              hipStream_t stream) {
    const int N = NN, E = EE, L = 5;
    const int*   x     = (const int*)d_in[0];
    const int*   ei    = (const int*)d_in[1];
    const int*   ea    = (const int*)d_in[2];
    const float* at    = (const float*)d_in[3];
    const float* bt    = (const float*)d_in[4];
    const float* w1    = (const float*)d_in[5];
    const float* b1    = (const float*)d_in[6];
    const float* w2    = (const float*)d_in[7];
    const float* b2    = (const float*)d_in[8];
    const float* gamma = (const float*)d_in[9];
    const float* beta  = (const float*)d_in[10];
    float* out = (float*)d_out;

    char* ws = (char*)d_ws;
    size_t off = 0;
    auto alloc = [&](size_t bytes) { char* p = ws + off; off = (off + bytes + 255) & ~(size_t)255; return p; };
    u16* buf_y    = (u16*)alloc((size_t)N * DP * 2);     // post-BN/relu state, bf16
    u16* buf_agg  = (u16*)alloc((size_t)N * DP * 2);
    float* buf_h  = (float*)alloc((size_t)N * DP * 4);   // raw (pre-BN) state, fp32
    u16* w1t      = (u16*)alloc((size_t)5 * HP * DP * 2);
    u16* w2t      = (u16*)alloc((size_t)5 * DP * HP * 2);
    int* deg      = (int*)alloc((size_t)N * 4);
    int* offs     = (int*)alloc((size_t)(N + 1) * 4);
    int* cursors  = (int*)alloc((size_t)N * 4);
    u32* vals     = (u32*)alloc((size_t)E * 4);
    int* bsums    = (int*)alloc(128 * 4);
    float* emb    = (float*)alloc(17 * DP * 4);
    float* stats  = (float*)alloc(2 * DP * 4);
    float* scale  = (float*)alloc(DP * 4);
    float* shift  = (float*)alloc(DP * 4);

    // CSR build (once per call; reused by all 5 layers)
    (void)hipMemsetAsync(deg, 0, (size_t)N * 4, stream);
    count_deg<<<(E + 255) / 256, 256, 0, stream>>>(ei, deg, E);
    const int nb = (N + 1023) / 1024;
    scan1<<<nb, 1024, 0, stream>>>(deg, offs, bsums, N);
    scan2<<<1, 128, 0, stream>>>(bsums, nb);
    scan3<<<(N + 1 + 1023) / 1024, 1024, 0, stream>>>(offs, bsums, N, E);
    (void)hipMemcpyAsync(cursors, offs, (size_t)N * 4, hipMemcpyDeviceToDevice, stream);
    fill_csr<<<(E + 255) / 256, 256, 0, stream>>>(ei, ea, cursors, vals, E);

    // weights -> bf16 transposed padded
    conv_w1<<<(5 * HP * DP + 255) / 256, 256, 0, stream>>>(w1, w1t);
    conv_w2<<<(5 * DP * HP + 255) / 256, 256, 0, stream>>>(w2, w2t);

    // layer-0 state
    atom_enc<<<N, DP, 0, stream>>>(x, at, buf_y);

    const int MBF = (N + 63) / 64;  // 1563 blocks
    for (int l = 0; l < L; ++l) {
        bond_enc<<<17, DP, 0, stream>>>(bt + (size_t)l * 4 * 6 * 300, emb);
        aggregate<<<(N * 64 + 255) / 256, 256, 0, stream>>>(
            buf_y, emb, offs, vals, buf_agg, N);
        (void)hipMemsetAsync(stats, 0, 2 * DP * 4, stream);
        fused_mlp<<<MBF, 256, 0, stream>>>(
            buf_agg,
            w1t + (size_t)l * HP * DP, w2t + (size_t)l * DP * HP,
            b1 + (size_t)l * 600, b2 + (size_t)l * 300,
            buf_h, stats, stats + DP, N);
        bn_ss<<<1, DP, 0, stream>>>(stats, gamma + (size_t)l * 300, beta + (size_t)l * 300, scale, shift, N);
        if (l < L - 1)
            bn_apply<<<N, DP, 0, stream>>>(buf_h, scale, shift, buf_y);
    }
    finalize<<<N, DP, 0, stream>>>(buf_h, scale, shift, out);
}

// Round 5
// 3390.118 us; speedup vs baseline: 1.3610x; 1.3610x over previous
//
#include <hip/hip_runtime.h>

// ---------------- types / helpers ----------------
typedef unsigned short u16;
typedef unsigned int   u32;
typedef __bf16 bf16x8 __attribute__((ext_vector_type(8)));
typedef float  f32x4  __attribute__((ext_vector_type(4)));

__device__ __forceinline__ u16 f2bf(float f) {
    u32 u = __builtin_bit_cast(u32, f);
    u = u + 0x7fffu + ((u >> 16) & 1u);
    return (u16)(u >> 16);
}
__device__ __forceinline__ float bflo(u32 u) { return __builtin_bit_cast(float, u << 16); }
__device__ __forceinline__ float bfhi(u32 u) { return __builtin_bit_cast(float, u & 0xffff0000u); }
__device__ __forceinline__ u32 pack2(float x, float y) { return (u32)f2bf(x) | ((u32)f2bf(y) << 16); }

#define NN 100000
#define EE 400000
#define DP 320   // padded D (300 -> 320)
#define HP 640   // padded 2D (600 -> 640)

// ---------------- preprocessing ----------------
__global__ void count_deg(const int* __restrict__ ei, int* __restrict__ deg, int E) {
    int e = blockIdx.x * 256 + threadIdx.x;
    if (e < E) atomicAdd(&deg[ei[E + e]], 1);
}

__global__ void scan1(const int* __restrict__ deg, int* __restrict__ out, int* __restrict__ bsums, int n) {
    __shared__ int lds[1024];
    int t = threadIdx.x;
    int i = blockIdx.x * 1024 + t;
    int v = (i < n) ? deg[i] : 0;
    lds[t] = v;
    __syncthreads();
    for (int d = 1; d < 1024; d <<= 1) {
        int add = (t >= d) ? lds[t - d] : 0;
        __syncthreads();
        lds[t] += add;
        __syncthreads();
    }
    if (i < n) out[i] = lds[t] - v;   // exclusive
    if (t == 1023) bsums[blockIdx.x] = lds[t];
}

__global__ void scan2(int* __restrict__ bsums, int nb) {
    __shared__ int lds[128];
    int t = threadIdx.x;
    int v = (t < nb) ? bsums[t] : 0;
    lds[t] = v;
    __syncthreads();
    for (int d = 1; d < 128; d <<= 1) {
        int add = (t >= d) ? lds[t - d] : 0;
        __syncthreads();
        lds[t] += add;
        __syncthreads();
    }
    if (t < nb) bsums[t] = lds[t] - v;
}

__global__ void scan3(int* __restrict__ out, const int* __restrict__ bsums, int n, int etot) {
    int i = blockIdx.x * 1024 + threadIdx.x;
    if (i < n) out[i] += bsums[blockIdx.x];
    else if (i == n) out[i] = etot;
}

__global__ void fill_csr(const int* __restrict__ ei, const int* __restrict__ ea,
                         int* __restrict__ cursors, u32* __restrict__ vals, int E) {
    int e = blockIdx.x * 256 + threadIdx.x;
    if (e >= E) return;
    int dst = ei[E + e];
    int src = ei[e];
    u32 code = (u32)((ea[e*4] & 1) | ((ea[e*4+1] & 1) << 1) | ((ea[e*4+2] & 1) << 2) | ((ea[e*4+3] & 1) << 3));
    int pos = atomicAdd(&cursors[dst], 1);
    vals[pos] = ((u32)src << 4) | code;
}

// W1 -> transposed padded bf16 (B^T layout): wt[l][n][k] = w1[l][k][n]
__global__ void conv_w1(const float* __restrict__ w, u16* __restrict__ wt) {
    int id = blockIdx.x * 256 + threadIdx.x;
    if (id >= 5 * HP * DP) return;
    int l = id / (HP * DP);
    int rem = id - l * (HP * DP);
    int n = rem / DP;
    int k = rem - n * DP;
    u16 v = 0;
    if (n < 600 && k < 300) v = f2bf(w[((size_t)l * 300 + k) * 600 + n]);
    wt[id] = v;
}
// W2 -> chunk-major bf16: wt[l][c][n][kk] = w2[l][c*32+kk][n]  (contiguous 20 KB per k-chunk)
__global__ void conv_w2(const float* __restrict__ w, u16* __restrict__ wt) {
    int id = blockIdx.x * 256 + threadIdx.x;
    if (id >= 5 * DP * HP) return;
    int l = id / (DP * HP);
    int rem = id - l * (DP * HP);
    int c = rem / (320 * 32);
    int r2 = rem - c * (320 * 32);
    int n = r2 >> 5;
    int kk = r2 & 31;
    int k = c * 32 + kk;
    u16 v = 0;
    if (n < 300 && k < 600) v = f2bf(w[((size_t)l * 600 + k) * 300 + n]);
    wt[id] = v;
}

// atom encoder -> y bf16 (layer-0 state is just the embedding sum)
__global__ void atom_enc(const int* __restrict__ x, const float* __restrict__ at, u16* __restrict__ y) {
    const int i = blockIdx.x;
    const int d = threadIdx.x; // 0..319
    __shared__ int xi[7];
    if (d < 7) xi[d] = x[i * 7 + d];
    __syncthreads();
    u16 v = 0;
    if (d < 300) {
        float s = 0.f;
        #pragma unroll
        for (int f = 0; f < 7; ++f) s += at[(f * 119 + xi[f]) * 300 + d];
        v = f2bf(s);
    }
    y[(size_t)i * DP + d] = v;
}

// per-layer bond embedding table: 16 codes + self-loop (index 16)
__global__ void bond_enc(const float* __restrict__ bt, float* __restrict__ emb) {
    const int c = blockIdx.x;  // 0..16
    const int d = threadIdx.x; // 0..319
    float s = 0.f;
    if (d < 300) {
        if (c < 16) {
            #pragma unroll
            for (int f = 0; f < 4; ++f) s += bt[(f * 6 + ((c >> f) & 1)) * 300 + d];
        } else {
            s = bt[4 * 300 + d];  // bond[0][4]
            #pragma unroll
            for (int f = 1; f < 4; ++f) s += bt[f * 6 * 300 + d];
        }
    }
    emb[c * DP + d] = s;
}

// stats -> BN (scale, shift)
__global__ void bn_ss(const float* __restrict__ stats, const float* __restrict__ gamma,
                      const float* __restrict__ beta, float* __restrict__ scale,
                      float* __restrict__ shift, int n) {
    int d = threadIdx.x;
    float sc = 0.f, sh = 0.f;
    if (d < 300) {
        float inv_n = 1.0f / (float)n;
        float mu = stats[d] * inv_n;
        float var = stats[DP + d] * inv_n - mu * mu;
        float inv = 1.0f / sqrtf(var + 1e-5f);
        sc = gamma[d] * inv;
        sh = beta[d] - mu * sc;
    }
    scale[d] = sc; shift[d] = sh;
}

// y[i][d] = bf16(relu(scale*h_raw + shift))   (pads: scale=shift=0, h pad -> 0)
__global__ void bn_apply(const float* __restrict__ hraw, const float* __restrict__ scale,
                         const float* __restrict__ shift, u16* __restrict__ y) {
    const int i = blockIdx.x;
    const int d = threadIdx.x;
    float v = fmaf(scale[d], hraw[(size_t)i * DP + d], shift[d]);
    y[(size_t)i * DP + d] = f2bf(fmaxf(v, 0.f));
}

// ---------------- aggregation: one wave per node, batch-4 edge unroll ----------------
__global__ void aggregate(const u16* __restrict__ y,
                          const float* __restrict__ emb,
                          const int* __restrict__ offs, const u32* __restrict__ vals,
                          u16* __restrict__ agg, const int n) {
    const int wid = (int)((blockIdx.x * (size_t)blockDim.x + threadIdx.x) >> 6);
    const int lane = threadIdx.x & 63;
    if (wid >= n) return;
    const int j0 = lane, j1 = lane + 64, j2 = lane + 128;
    const bool has2 = (lane < 32);

    float a0x = 0.f, a0y = 0.f, a1x = 0.f, a1y = 0.f, a2x = 0.f, a2y = 0.f;

    auto addrow = [&](u32 u0, u32 u1, u32 u2, const float* er) {
        float2 e0 = *(const float2*)(er + 2 * j0);
        float2 e1 = *(const float2*)(er + 2 * j1);
        a0x += bflo(u0) + e0.x;  a0y += bfhi(u0) + e0.y;
        a1x += bflo(u1) + e1.x;  a1y += bfhi(u1) + e1.y;
        if (has2) {
            float2 e2 = *(const float2*)(er + 2 * j2);
            a2x += bflo(u2) + e2.x;  a2y += bfhi(u2) + e2.y;
        }
    };

    {   // self loop
        const u32* r = (const u32*)y + (size_t)wid * (DP / 2);
        addrow(r[j0], r[j1], has2 ? r[j2] : 0u, emb + 16 * DP);
    }
    int e = offs[wid];
    const int t = offs[wid + 1];
    for (; e + 4 <= t; e += 4) {
        u32 v0 = vals[e], v1 = vals[e + 1], v2 = vals[e + 2], v3 = vals[e + 3];
        const u32* r0 = (const u32*)y + (size_t)(v0 >> 4) * (DP / 2);
        const u32* r1 = (const u32*)y + (size_t)(v1 >> 4) * (DP / 2);
        const u32* r2 = (const u32*)y + (size_t)(v2 >> 4) * (DP / 2);
        const u32* r3 = (const u32*)y + (size_t)(v3 >> 4) * (DP / 2);
        u32 x00 = r0[j0], x01 = r0[j1], x02 = has2 ? r0[j2] : 0u;
        u32 x10 = r1[j0], x11 = r1[j1], x12 = has2 ? r1[j2] : 0u;
        u32 x20 = r2[j0], x21 = r2[j1], x22 = has2 ? r2[j2] : 0u;
        u32 x30 = r3[j0], x31 = r3[j1], x32 = has2 ? r3[j2] : 0u;
        addrow(x00, x01, x02, emb + (v0 & 15u) * DP);
        addrow(x10, x11, x12, emb + (v1 & 15u) * DP);
        addrow(x20, x21, x22, emb + (v2 & 15u) * DP);
        addrow(x30, x31, x32, emb + (v3 & 15u) * DP);
    }
    for (; e < t; ++e) {
        u32 v = vals[e];
        const u32* r = (const u32*)y + (size_t)(v >> 4) * (DP / 2);
        addrow(r[j0], r[j1], has2 ? r[j2] : 0u, emb + (v & 15u) * DP);
    }

    u32* outp = (u32*)agg + (size_t)wid * (DP / 2);
    outp[j0] = pack2(a0x, a0y);
    outp[j1] = pack2(a1x, a1y);
    if (has2) outp[j2] = pack2(a2x, a2y);
}

// ---------------- fused MLP v3: A-frags in regs, W staged via LDS ----------------
// Block = 64 rows, 4 waves; wave owns 16 rows x all 320 out cols.
// Per 32-hidden-col chunk: cooperatively stage W1 slice (20KB, contiguous) and
// W2 chunk-major slice (20KB, contiguous) into padded LDS; all 4 waves read
// fragments from LDS (2-way-max bank aliasing). hid slab per-wave-private.
// 51.7 KB LDS, VGPR<=170 -> 3 blocks/CU, barriers scope 4 waves only.
#define W1S 328    // W1 slab row stride (u16): 656 B -> granule walk +1, conflict-free
#define W2S 40     // W2 slab row stride (u16): 80 B
#define HSTR 40    // hid row stride (u16)

__global__ __launch_bounds__(256, 3) void fused_mlp(
    const u16* __restrict__ A,      // agg [N][320] bf16
    const u16* __restrict__ W1t,    // [640][320] bf16 (W1^T)
    const u16* __restrict__ W2c,    // [20][320][32] bf16 (W2 chunk-major)
    const float* __restrict__ b1g,  // [600]
    const float* __restrict__ b2g,  // [300]
    float* __restrict__ H,          // h_raw [N][320] fp32
    float* __restrict__ st1, float* __restrict__ st2,
    const int M) {

    __shared__ __align__(16) u16 w1s[32 * W1S];    // 20992 B
    __shared__ __align__(16) u16 w2s[320 * W2S];   // 25600 B
    __shared__ __align__(16) u16 hid[64 * HSTR];   //  5120 B

    const int tid  = threadIdx.x;
    const int wid  = tid >> 6;
    const int lane = tid & 63;
    const int l15  = lane & 15;
    const int q    = lane >> 4;
    const int bm   = blockIdx.x * 64;

    // ---- A fragments: 16 rows x 320 k, direct from global (one-time scatter) ----
    const int row_a = bm + wid * 16 + l15;
    const bool rv = (row_a < M);
    const u16* arow = A + (size_t)row_a * DP + q * 8;
    bf16x8 afr[10];
    #pragma unroll
    for (int kt = 0; kt < 10; ++kt) {
        uint4 tv; tv.x = tv.y = tv.z = tv.w = 0;
        if (rv) tv = *(const uint4*)(arow + kt * 32);
        afr[kt] = __builtin_bit_cast(bf16x8, tv);
    }

    f32x4 acc2[20];
    #pragma unroll
    for (int nf = 0; nf < 20; ++nf) acc2[nf] = (f32x4){0.f, 0.f, 0.f, 0.f};

    u16* hw = &hid[(wid * 16) * HSTR];   // per-wave-private slab

    for (int c = 0; c < 20; ++c) {
        __syncthreads();   // all waves done reading previous chunk's slabs
        // ---- cooperative staging: both slices are contiguous 20 KB ----
        {
            const u16* g1 = W1t + (size_t)c * 32 * DP;
            const u16* g2 = W2c + (size_t)c * 320 * 32;
            #pragma unroll
            for (int i = 0; i < 5; ++i) {
                int u = tid + i * 256;                 // 0..1279
                uint4 v1 = *(const uint4*)(g1 + (size_t)u * 8);
                *(uint4*)&w1s[(u / 40) * W1S + (u % 40) * 8] = v1;
            }
            #pragma unroll
            for (int i = 0; i < 5; ++i) {
                int u = tid + i * 256;
                uint4 v2 = *(const uint4*)(g2 + (size_t)u * 8);
                *(uint4*)&w2s[(u >> 2) * W2S + (u & 3) * 8] = v2;
            }
        }
        __syncthreads();

        // ---- GEMM1: 16 rows x 32 hidden cols ----
        f32x4 acc1[2] = {(f32x4){0.f,0.f,0.f,0.f}, (f32x4){0.f,0.f,0.f,0.f}};
        #pragma unroll
        for (int kt = 0; kt < 10; ++kt) {
            bf16x8 wa = __builtin_bit_cast(bf16x8, *(const uint4*)&w1s[l15 * W1S + kt * 32 + q * 8]);
            bf16x8 wb = __builtin_bit_cast(bf16x8, *(const uint4*)&w1s[(16 + l15) * W1S + kt * 32 + q * 8]);
            acc1[0] = __builtin_amdgcn_mfma_f32_16x16x32_bf16(afr[kt], wa, acc1[0], 0, 0, 0);
            acc1[1] = __builtin_amdgcn_mfma_f32_16x16x32_bf16(afr[kt], wb, acc1[1], 0, 0, 0);
        }
        // bias + relu -> private hid slab (C-layout: col=l15, row=q*4+r)
        #pragma unroll
        for (int h = 0; h < 2; ++h) {
            int gcol = c * 32 + h * 16 + l15;
            float bb = (gcol < 600) ? b1g[gcol] : 0.f;
            #pragma unroll
            for (int r = 0; r < 4; ++r) {
                float v = fmaxf(acc1[h][r] + bb, 0.f);
                hw[(q * 4 + r) * HSTR + h * 16 + l15] = f2bf(v);
            }
        }
        // transpose readback (same wave; lgkmcnt only, no barrier)
        bf16x8 a2 = __builtin_bit_cast(bf16x8, *(const uint4*)&hw[l15 * HSTR + q * 8]);
        // ---- GEMM2: accumulate 16 rows x 320 cols over this 32-k chunk ----
        #pragma unroll
        for (int nf = 0; nf < 20; ++nf) {
            bf16x8 wf = __builtin_bit_cast(bf16x8, *(const uint4*)&w2s[(nf * 16 + l15) * W2S + q * 8]);
            acc2[nf] = __builtin_amdgcn_mfma_f32_16x16x32_bf16(a2, wf, acc2[nf], 0, 0, 0);
        }
    }

    // ---- epilogue: bias2, store fp32 raw h, BN stats via global atomics ----
    #pragma unroll
    for (int nf = 0; nf < 20; ++nf) {
        const int col = nf * 16 + l15;
        const float bb = (col < 300) ? b2g[col] : 0.f;
        float s1 = 0.f, s2 = 0.f;
        #pragma unroll
        for (int r = 0; r < 4; ++r) {
            const int row = bm + wid * 16 + q * 4 + r;
            if (row < M) {
                float v = acc2[nf][r] + bb;
                H[(size_t)row * DP + col] = v;
                s1 += v; s2 += v * v;
            }
        }
        s1 += __shfl_xor(s1, 16); s1 += __shfl_xor(s1, 32);
        s2 += __shfl_xor(s2, 16); s2 += __shfl_xor(s2, 32);
        if (q == 0) { atomicAdd(&st1[col], s1); atomicAdd(&st2[col], s2); }
    }
}

// final: d_out[i][d] = scale[d]*raw[i][d] + shift[d]  (no relu, fp32 in/out)
__global__ void finalize(const float* __restrict__ hraw, const float* __restrict__ scale,
                         const float* __restrict__ shift, float* __restrict__ out) {
    const int i = blockIdx.x;
    const int d = threadIdx.x;
    if (d < 300) {
        float x = hraw[(size_t)i * DP + d];
        out[(size_t)i * 300 + d] = fmaf(scale[d], x, shift[d]);
    }
}

// ---------------- launcher ----------------
extern "C" void kernel_launch(void* const* d_in, const int* in_sizes, int n_in,
                              void* d_out, int out_size, void* d_ws, size_t ws_size,
                              hipStream_t stream) {
    const int N = NN, E = EE, L = 5;
    const int*   x     = (const int*)d_in[0];
    const int*   ei    = (const int*)d_in[1];
    const int*   ea    = (const int*)d_in[2];
    const float* at    = (const float*)d_in[3];
    const float* bt    = (const float*)d_in[4];
    const float* w1    = (const float*)d_in[5];
    const float* b1    = (const float*)d_in[6];
    const float* w2    = (const float*)d_in[7];
    const float* b2    = (const float*)d_in[8];
    const float* gamma = (const float*)d_in[9];
    const float* beta  = (const float*)d_in[10];
    float* out = (float*)d_out;

    char* ws = (char*)d_ws;
    size_t off = 0;
    auto alloc = [&](size_t bytes) { char* p = ws + off; off = (off + bytes + 255) & ~(size_t)255; return p; };
    u16* buf_y    = (u16*)alloc((size_t)N * DP * 2);     // post-BN/relu state, bf16
    u16* buf_agg  = (u16*)alloc((size_t)N * DP * 2);
    float* buf_h  = (float*)alloc((size_t)N * DP * 4);   // raw (pre-BN) state, fp32
    u16* w1t      = (u16*)alloc((size_t)5 * HP * DP * 2);
    u16* w2c      = (u16*)alloc((size_t)5 * DP * HP * 2);
    int* deg      = (int*)alloc((size_t)N * 4);
    int* offs     = (int*)alloc((size_t)(N + 1) * 4);
    int* cursors  = (int*)alloc((size_t)N * 4);
    u32* vals     = (u32*)alloc((size_t)E * 4);
    int* bsums    = (int*)alloc(128 * 4);
    float* emb    = (float*)alloc(17 * DP * 4);
    float* stats  = (float*)alloc(2 * DP * 4);
    float* scale  = (float*)alloc(DP * 4);
    float* shift  = (float*)alloc(DP * 4);

    // CSR build (once per call; reused by all 5 layers)
    (void)hipMemsetAsync(deg, 0, (size_t)N * 4, stream);
    count_deg<<<(E + 255) / 256, 256, 0, stream>>>(ei, deg, E);
    const int nb = (N + 1023) / 1024;
    scan1<<<nb, 1024, 0, stream>>>(deg, offs, bsums, N);
    scan2<<<1, 128, 0, stream>>>(bsums, nb);
    scan3<<<(N + 1 + 1023) / 1024, 1024, 0, stream>>>(offs, bsums, N, E);
    (void)hipMemcpyAsync(cursors, offs, (size_t)N * 4, hipMemcpyDeviceToDevice, stream);
    fill_csr<<<(E + 255) / 256, 256, 0, stream>>>(ei, ea, cursors, vals, E);

    // weights -> bf16 (W1 transposed padded; W2 chunk-major)
    conv_w1<<<(5 * HP * DP + 255) / 256, 256, 0, stream>>>(w1, w1t);
    conv_w2<<<(5 * DP * HP + 255) / 256, 256, 0, stream>>>(w2, w2c);

    // layer-0 state
    atom_enc<<<N, DP, 0, stream>>>(x, at, buf_y);

    const int MBF = (N + 63) / 64;  // 1563 blocks
    for (int l = 0; l < L; ++l) {
        bond_enc<<<17, DP, 0, stream>>>(bt + (size_t)l * 4 * 6 * 300, emb);
        aggregate<<<(N * 64 + 255) / 256, 256, 0, stream>>>(
            buf_y, emb, offs, vals, buf_agg, N);
        (void)hipMemsetAsync(stats, 0, 2 * DP * 4, stream);
        fused_mlp<<<MBF, 256, 0, stream>>>(
            buf_agg,
            w1t + (size_t)l * HP * DP, w2c + (size_t)l * DP * HP,
            b1 + (size_t)l * 600, b2 + (size_t)l * 300,
            buf_h, stats, stats + DP, N);
        bn_ss<<<1, DP, 0, stream>>>(stats, gamma + (size_t)l * 300, beta + (size_t)l * 300, scale, shift, N);
        if (l < L - 1)
            bn_apply<<<N, DP, 0, stream>>>(buf_h, scale, shift, buf_y);
    }
    finalize<<<N, DP, 0, stream>>>(buf_h, scale, shift, out);
}

// Round 6
// 2213.631 us; speedup vs baseline: 2.0844x; 1.5315x over previous
//
#include <hip/hip_runtime.h>

// ---------------- types / helpers ----------------
typedef unsigned short u16;
typedef unsigned int   u32;
typedef __bf16 bf16x8 __attribute__((ext_vector_type(8)));
typedef float  f32x4  __attribute__((ext_vector_type(4)));

__device__ __forceinline__ u16 f2bf(float f) {
    u32 u = __builtin_bit_cast(u32, f);
    u = u + 0x7fffu + ((u >> 16) & 1u);
    return (u16)(u >> 16);
}
__device__ __forceinline__ float bflo(u32 u) { return __builtin_bit_cast(float, u << 16); }
__device__ __forceinline__ float bfhi(u32 u) { return __builtin_bit_cast(float, u & 0xffff0000u); }
__device__ __forceinline__ u32 pack2(float x, float y) { return (u32)f2bf(x) | ((u32)f2bf(y) << 16); }

#define NN 100000
#define EE 400000
#define DP 320   // padded D (300 -> 320)
#define HP 640   // padded 2D (600 -> 640)

// ---------------- preprocessing ----------------
__global__ void count_deg(const int* __restrict__ ei, int* __restrict__ deg, int E) {
    int e = blockIdx.x * 256 + threadIdx.x;
    if (e < E) atomicAdd(&deg[ei[E + e]], 1);
}

__global__ void scan1(const int* __restrict__ deg, int* __restrict__ out, int* __restrict__ bsums, int n) {
    __shared__ int lds[1024];
    int t = threadIdx.x;
    int i = blockIdx.x * 1024 + t;
    int v = (i < n) ? deg[i] : 0;
    lds[t] = v;
    __syncthreads();
    for (int d = 1; d < 1024; d <<= 1) {
        int add = (t >= d) ? lds[t - d] : 0;
        __syncthreads();
        lds[t] += add;
        __syncthreads();
    }
    if (i < n) out[i] = lds[t] - v;   // exclusive
    if (t == 1023) bsums[blockIdx.x] = lds[t];
}

__global__ void scan2(int* __restrict__ bsums, int nb) {
    __shared__ int lds[128];
    int t = threadIdx.x;
    int v = (t < nb) ? bsums[t] : 0;
    lds[t] = v;
    __syncthreads();
    for (int d = 1; d < 128; d <<= 1) {
        int add = (t >= d) ? lds[t - d] : 0;
        __syncthreads();
        lds[t] += add;
        __syncthreads();
    }
    if (t < nb) bsums[t] = lds[t] - v;
}

__global__ void scan3(int* __restrict__ out, const int* __restrict__ bsums, int n, int etot) {
    int i = blockIdx.x * 1024 + threadIdx.x;
    if (i < n) out[i] += bsums[blockIdx.x];
    else if (i == n) out[i] = etot;
}

__global__ void fill_csr(const int* __restrict__ ei, const int* __restrict__ ea,
                         int* __restrict__ cursors, u32* __restrict__ vals, int E) {
    int e = blockIdx.x * 256 + threadIdx.x;
    if (e >= E) return;
    int dst = ei[E + e];
    int src = ei[e];
    u32 code = (u32)((ea[e*4] & 1) | ((ea[e*4+1] & 1) << 1) | ((ea[e*4+2] & 1) << 2) | ((ea[e*4+3] & 1) << 3));
    int pos = atomicAdd(&cursors[dst], 1);
    vals[pos] = ((u32)src << 4) | code;
}

// W1 -> transposed padded bf16 (B^T layout): wt[l][n][k] = w1[l][k][n]
__global__ void conv_w1(const float* __restrict__ w, u16* __restrict__ wt) {
    int id = blockIdx.x * 256 + threadIdx.x;
    if (id >= 5 * HP * DP) return;
    int l = id / (HP * DP);
    int rem = id - l * (HP * DP);
    int n = rem / DP;
    int k = rem - n * DP;
    u16 v = 0;
    if (n < 600 && k < 300) v = f2bf(w[((size_t)l * 300 + k) * 600 + n]);
    wt[id] = v;
}
// W2 -> chunk-major bf16: wt[l][c][n][kk] = w2[l][c*32+kk][n]  (contiguous 20 KB per k-chunk)
__global__ void conv_w2(const float* __restrict__ w, u16* __restrict__ wt) {
    int id = blockIdx.x * 256 + threadIdx.x;
    if (id >= 5 * DP * HP) return;
    int l = id / (DP * HP);
    int rem = id - l * (DP * HP);
    int c = rem / (320 * 32);
    int r2 = rem - c * (320 * 32);
    int n = r2 >> 5;
    int kk = r2 & 31;
    int k = c * 32 + kk;
    u16 v = 0;
    if (n < 300 && k < 600) v = f2bf(w[((size_t)l * 600 + k) * 300 + n]);
    wt[id] = v;
}

// atom encoder -> y bf16 (layer-0 state is just the embedding sum)
__global__ void atom_enc(const int* __restrict__ x, const float* __restrict__ at, u16* __restrict__ y) {
    const int i = blockIdx.x;
    const int d = threadIdx.x; // 0..319
    __shared__ int xi[7];
    if (d < 7) xi[d] = x[i * 7 + d];
    __syncthreads();
    u16 v = 0;
    if (d < 300) {
        float s = 0.f;
        #pragma unroll
        for (int f = 0; f < 7; ++f) s += at[(f * 119 + xi[f]) * 300 + d];
        v = f2bf(s);
    }
    y[(size_t)i * DP + d] = v;
}

// per-layer bond embedding table: 16 codes + self-loop (index 16)
__global__ void bond_enc(const float* __restrict__ bt, float* __restrict__ emb) {
    const int c = blockIdx.x;  // 0..16
    const int d = threadIdx.x; // 0..319
    float s = 0.f;
    if (d < 300) {
        if (c < 16) {
            #pragma unroll
            for (int f = 0; f < 4; ++f) s += bt[(f * 6 + ((c >> f) & 1)) * 300 + d];
        } else {
            s = bt[4 * 300 + d];  // bond[0][4]
            #pragma unroll
            for (int f = 1; f < 4; ++f) s += bt[f * 6 * 300 + d];
        }
    }
    emb[c * DP + d] = s;
}

// stats -> BN (scale, shift)
__global__ void bn_ss(const float* __restrict__ stats, const float* __restrict__ gamma,
                      const float* __restrict__ beta, float* __restrict__ scale,
                      float* __restrict__ shift, int n) {
    int d = threadIdx.x;
    float sc = 0.f, sh = 0.f;
    if (d < 300) {
        float inv_n = 1.0f / (float)n;
        float mu = stats[d] * inv_n;
        float var = stats[DP + d] * inv_n - mu * mu;
        float inv = 1.0f / sqrtf(var + 1e-5f);
        sc = gamma[d] * inv;
        sh = beta[d] - mu * sc;
    }
    scale[d] = sc; shift[d] = sh;
}

// y[i][d] = bf16(relu(scale*h_raw + shift))   (pads: scale=shift=0, h pad -> 0)
__global__ void bn_apply(const float* __restrict__ hraw, const float* __restrict__ scale,
                         const float* __restrict__ shift, u16* __restrict__ y) {
    const int i = blockIdx.x;
    const int d = threadIdx.x;
    float v = fmaf(scale[d], hraw[(size_t)i * DP + d], shift[d]);
    y[(size_t)i * DP + d] = f2bf(fmaxf(v, 0.f));
}

// ---------------- aggregation: one wave per node, batch-4 edge unroll ----------------
__global__ void aggregate(const u16* __restrict__ y,
                          const float* __restrict__ emb,
                          const int* __restrict__ offs, const u32* __restrict__ vals,
                          u16* __restrict__ agg, const int n) {
    const int wid = (int)((blockIdx.x * (size_t)blockDim.x + threadIdx.x) >> 6);
    const int lane = threadIdx.x & 63;
    if (wid >= n) return;
    const int j0 = lane, j1 = lane + 64, j2 = lane + 128;
    const bool has2 = (lane < 32);

    float a0x = 0.f, a0y = 0.f, a1x = 0.f, a1y = 0.f, a2x = 0.f, a2y = 0.f;

    auto addrow = [&](u32 u0, u32 u1, u32 u2, const float* er) {
        float2 e0 = *(const float2*)(er + 2 * j0);
        float2 e1 = *(const float2*)(er + 2 * j1);
        a0x += bflo(u0) + e0.x;  a0y += bfhi(u0) + e0.y;
        a1x += bflo(u1) + e1.x;  a1y += bfhi(u1) + e1.y;
        if (has2) {
            float2 e2 = *(const float2*)(er + 2 * j2);
            a2x += bflo(u2) + e2.x;  a2y += bfhi(u2) + e2.y;
        }
    };

    {   // self loop
        const u32* r = (const u32*)y + (size_t)wid * (DP / 2);
        addrow(r[j0], r[j1], has2 ? r[j2] : 0u, emb + 16 * DP);
    }
    int e = offs[wid];
    const int t = offs[wid + 1];
    for (; e + 4 <= t; e += 4) {
        u32 v0 = vals[e], v1 = vals[e + 1], v2 = vals[e + 2], v3 = vals[e + 3];
        const u32* r0 = (const u32*)y + (size_t)(v0 >> 4) * (DP / 2);
        const u32* r1 = (const u32*)y + (size_t)(v1 >> 4) * (DP / 2);
        const u32* r2 = (const u32*)y + (size_t)(v2 >> 4) * (DP / 2);
        const u32* r3 = (const u32*)y + (size_t)(v3 >> 4) * (DP / 2);
        u32 x00 = r0[j0], x01 = r0[j1], x02 = has2 ? r0[j2] : 0u;
        u32 x10 = r1[j0], x11 = r1[j1], x12 = has2 ? r1[j2] : 0u;
        u32 x20 = r2[j0], x21 = r2[j1], x22 = has2 ? r2[j2] : 0u;
        u32 x30 = r3[j0], x31 = r3[j1], x32 = has2 ? r3[j2] : 0u;
        addrow(x00, x01, x02, emb + (v0 & 15u) * DP);
        addrow(x10, x11, x12, emb + (v1 & 15u) * DP);
        addrow(x20, x21, x22, emb + (v2 & 15u) * DP);
        addrow(x30, x31, x32, emb + (v3 & 15u) * DP);
    }
    for (; e < t; ++e) {
        u32 v = vals[e];
        const u32* r = (const u32*)y + (size_t)(v >> 4) * (DP / 2);
        addrow(r[j0], r[j1], has2 ? r[j2] : 0u, emb + (v & 15u) * DP);
    }

    u32* outp = (u32*)agg + (size_t)wid * (DP / 2);
    outp[j0] = pack2(a0x, a0y);
    outp[j1] = pack2(a1x, a1y);
    if (has2) outp[j2] = pack2(a2x, a2y);
}

// ---------------- fused MLP v4: 8 waves, reg-prefetched W staging ----------------
// Block = 64 rows, 512 threads = 4 m-groups x 2 n-halves.
// Wave (mg,nh): GEMM1 = 16 rows x 16 hidden cols; GEMM2 = 16 rows x 160 out cols.
// W slices prefetched into registers during compute of the previous chunk
// (vmcnt wait lands at the next chunk's ds_write) -- R3's proven hiding pattern,
// now at 51.7 KB LDS -> 2 blocks/CU (16 waves/CU) for cross-block overlap.
#define W1S 328    // W1 slab row stride (u16)
#define W2S 40     // W2 slab row stride (u16)
#define HSTR 40    // hid row stride (u16)

__global__ __launch_bounds__(512, 4) void fused_mlp(
    const u16* __restrict__ A,      // agg [N][320] bf16
    const u16* __restrict__ W1t,    // [640][320] bf16 (W1^T)
    const u16* __restrict__ W2c,    // [20][320][32] bf16 (W2 chunk-major)
    const float* __restrict__ b1g,  // [600]
    const float* __restrict__ b2g,  // [300]
    float* __restrict__ H,          // h_raw [N][320] fp32
    float* __restrict__ st1, float* __restrict__ st2,
    const int M) {

    __shared__ __align__(16) u16 w1s[32 * W1S];    // 20992 B
    __shared__ __align__(16) u16 w2s[320 * W2S];   // 25600 B
    __shared__ __align__(16) u16 hid[64 * HSTR];   //  5120 B

    const int tid  = threadIdx.x;
    const int wid  = tid >> 6;
    const int lane = tid & 63;
    const int l15  = lane & 15;
    const int q    = lane >> 4;
    const int mg   = wid >> 1;    // 0..3: rows [mg*16, mg*16+16)
    const int nh   = wid & 1;     // n-half
    const int bm   = blockIdx.x * 64;
    const bool lo  = (tid < 256);

    // ---- A fragments: 16 rows x 320 k, direct from global (one-time) ----
    const int row_a = bm + mg * 16 + l15;
    const bool rv = (row_a < M);
    const u16* arow = A + (size_t)row_a * DP + q * 8;
    bf16x8 afr[10];
    #pragma unroll
    for (int kt = 0; kt < 10; ++kt) {
        uint4 tv; tv.x = tv.y = tv.z = tv.w = 0;
        if (rv) tv = *(const uint4*)(arow + kt * 32);
        afr[kt] = __builtin_bit_cast(bf16x8, tv);
    }

    f32x4 acc2[10];
    #pragma unroll
    for (int nf = 0; nf < 10; ++nf) acc2[nf] = (f32x4){0.f, 0.f, 0.f, 0.f};

    // ---- W prefetch registers ----
    uint4 pw1a, pw1b, pw1c, pw2a, pw2b, pw2c;
    {
        const u16* g1 = W1t;
        const u16* g2 = W2c;
        pw1a = *(const uint4*)(g1 + (size_t)tid * 8);
        pw1b = *(const uint4*)(g1 + (size_t)(tid + 512) * 8);
        pw2a = *(const uint4*)(g2 + (size_t)tid * 8);
        pw2b = *(const uint4*)(g2 + (size_t)(tid + 512) * 8);
        if (lo) {
            pw1c = *(const uint4*)(g1 + (size_t)(tid + 1024) * 8);
            pw2c = *(const uint4*)(g2 + (size_t)(tid + 1024) * 8);
        }
    }
    const int u0 = tid, u1 = tid + 512, u2 = tid + 1024;

    for (int c = 0; c < 20; ++c) {
        __syncthreads();   // B_a: all waves done reading slabs of chunk c-1
        // ---- commit prefetched chunk c to LDS (vmcnt wait lands here) ----
        *(uint4*)&w1s[(u0 / 40) * W1S + (u0 % 40) * 8] = pw1a;
        *(uint4*)&w1s[(u1 / 40) * W1S + (u1 % 40) * 8] = pw1b;
        *(uint4*)&w2s[(u0 >> 2) * W2S + (u0 & 3) * 8] = pw2a;
        *(uint4*)&w2s[(u1 >> 2) * W2S + (u1 & 3) * 8] = pw2b;
        if (lo) {
            *(uint4*)&w1s[(u2 / 40) * W1S + (u2 % 40) * 8] = pw1c;
            *(uint4*)&w2s[(u2 >> 2) * W2S + (u2 & 3) * 8] = pw2c;
        }
        __syncthreads();   // B_b: slabs ready

        // ---- issue prefetch for chunk c+1 (consumed at next B_a) ----
        if (c < 19) {
            const u16* g1 = W1t + (size_t)(c + 1) * 32 * DP;
            const u16* g2 = W2c + (size_t)(c + 1) * 320 * 32;
            pw1a = *(const uint4*)(g1 + (size_t)u0 * 8);
            pw1b = *(const uint4*)(g1 + (size_t)u1 * 8);
            pw2a = *(const uint4*)(g2 + (size_t)u0 * 8);
            pw2b = *(const uint4*)(g2 + (size_t)u1 * 8);
            if (lo) {
                pw1c = *(const uint4*)(g1 + (size_t)u2 * 8);
                pw2c = *(const uint4*)(g2 + (size_t)u2 * 8);
            }
        }

        // ---- GEMM1: 16 rows x 16 hidden cols (this wave's n-half) ----
        f32x4 acc1 = (f32x4){0.f, 0.f, 0.f, 0.f};
        #pragma unroll
        for (int kt = 0; kt < 10; ++kt) {
            bf16x8 wa = __builtin_bit_cast(bf16x8, *(const uint4*)&w1s[(nh * 16 + l15) * W1S + kt * 32 + q * 8]);
            acc1 = __builtin_amdgcn_mfma_f32_16x16x32_bf16(afr[kt], wa, acc1, 0, 0, 0);
        }
        // bias + relu -> shared hid slab (C-layout: col=l15, row=q*4+r)
        {
            int gcol = c * 32 + nh * 16 + l15;
            float bb = (gcol < 600) ? b1g[gcol] : 0.f;
            #pragma unroll
            for (int r = 0; r < 4; ++r) {
                float v = fmaxf(acc1[r] + bb, 0.f);
                hid[(mg * 16 + q * 4 + r) * HSTR + nh * 16 + l15] = f2bf(v);
            }
        }
        __syncthreads();   // B_c: hid (both halves) ready

        // ---- GEMM2: 16 rows x 160 out cols over this 32-k chunk ----
        bf16x8 a2 = __builtin_bit_cast(bf16x8, *(const uint4*)&hid[(mg * 16 + l15) * HSTR + q * 8]);
        #pragma unroll
        for (int nf = 0; nf < 10; ++nf) {
            bf16x8 wf = __builtin_bit_cast(bf16x8, *(const uint4*)&w2s[(nh * 160 + nf * 16 + l15) * W2S + q * 8]);
            acc2[nf] = __builtin_amdgcn_mfma_f32_16x16x32_bf16(a2, wf, acc2[nf], 0, 0, 0);
        }
    }

    // ---- epilogue: bias2, store fp32 raw h, BN stats via global atomics ----
    #pragma unroll
    for (int nf = 0; nf < 10; ++nf) {
        const int col = nh * 160 + nf * 16 + l15;
        const float bb = (col < 300) ? b2g[col] : 0.f;
        float s1 = 0.f, s2 = 0.f;
        #pragma unroll
        for (int r = 0; r < 4; ++r) {
            const int row = bm + mg * 16 + q * 4 + r;
            if (row < M) {
                float v = acc2[nf][r] + bb;
                H[(size_t)row * DP + col] = v;
                s1 += v; s2 += v * v;
            }
        }
        s1 += __shfl_xor(s1, 16); s1 += __shfl_xor(s1, 32);
        s2 += __shfl_xor(s2, 16); s2 += __shfl_xor(s2, 32);
        if (q == 0) { atomicAdd(&st1[col], s1); atomicAdd(&st2[col], s2); }
    }
}

// final: d_out[i][d] = scale[d]*raw[i][d] + shift[d]  (no relu, fp32 in/out)
__global__ void finalize(const float* __restrict__ hraw, const float* __restrict__ scale,
                         const float* __restrict__ shift, float* __restrict__ out) {
    const int i = blockIdx.x;
    const int d = threadIdx.x;
    if (d < 300) {
        float x = hraw[(size_t)i * DP + d];
        out[(size_t)i * 300 + d] = fmaf(scale[d], x, shift[d]);
    }
}

// ---------------- launcher ----------------
extern "C" void kernel_launch(void* const* d_in, const int* in_sizes, int n_in,
                              void* d_out, int out_size, void* d_ws, size_t ws_size,
                              hipStream_t stream) {
    const int N = NN, E = EE, L = 5;
    const int*   x     = (const int*)d_in[0];
    const int*   ei    = (const int*)d_in[1];
    const int*   ea    = (const int*)d_in[2];
    const float* at    = (const float*)d_in[3];
    const float* bt    = (const float*)d_in[4];
    const float* w1    = (const float*)d_in[5];
    const float* b1    = (const float*)d_in[6];
    const float* w2    = (const float*)d_in[7];
    const float* b2    = (const float*)d_in[8];
    const float* gamma = (const float*)d_in[9];
    const float* beta  = (const float*)d_in[10];
    float* out = (float*)d_out;

    char* ws = (char*)d_ws;
    size_t off = 0;
    auto alloc = [&](size_t bytes) { char* p = ws + off; off = (off + bytes + 255) & ~(size_t)255; return p; };
    u16* buf_y    = (u16*)alloc((size_t)N * DP * 2);     // post-BN/relu state, bf16
    u16* buf_agg  = (u16*)alloc((size_t)N * DP * 2);
    float* buf_h  = (float*)alloc((size_t)N * DP * 4);   // raw (pre-BN) state, fp32
    u16* w1t      = (u16*)alloc((size_t)5 * HP * DP * 2);
    u16* w2c      = (u16*)alloc((size_t)5 * DP * HP * 2);
    int* deg      = (int*)alloc((size_t)N * 4);
    int* offs     = (int*)alloc((size_t)(N + 1) * 4);
    int* cursors  = (int*)alloc((size_t)N * 4);
    u32* vals     = (u32*)alloc((size_t)E * 4);
    int* bsums    = (int*)alloc(128 * 4);
    float* emb    = (float*)alloc(17 * DP * 4);
    float* stats  = (float*)alloc(2 * DP * 4);
    float* scale  = (float*)alloc(DP * 4);
    float* shift  = (float*)alloc(DP * 4);

    // CSR build (once per call; reused by all 5 layers)
    (void)hipMemsetAsync(deg, 0, (size_t)N * 4, stream);
    count_deg<<<(E + 255) / 256, 256, 0, stream>>>(ei, deg, E);
    const int nb = (N + 1023) / 1024;
    scan1<<<nb, 1024, 0, stream>>>(deg, offs, bsums, N);
    scan2<<<1, 128, 0, stream>>>(bsums, nb);
    scan3<<<(N + 1 + 1023) / 1024, 1024, 0, stream>>>(offs, bsums, N, E);
    (void)hipMemcpyAsync(cursors, offs, (size_t)N * 4, hipMemcpyDeviceToDevice, stream);
    fill_csr<<<(E + 255) / 256, 256, 0, stream>>>(ei, ea, cursors, vals, E);

    // weights -> bf16 (W1 transposed padded; W2 chunk-major)
    conv_w1<<<(5 * HP * DP + 255) / 256, 256, 0, stream>>>(w1, w1t);
    conv_w2<<<(5 * DP * HP + 255) / 256, 256, 0, stream>>>(w2, w2c);

    // layer-0 state
    atom_enc<<<N, DP, 0, stream>>>(x, at, buf_y);

    const int MBF = (N + 63) / 64;  // 1563 blocks
    for (int l = 0; l < L; ++l) {
        bond_enc<<<17, DP, 0, stream>>>(bt + (size_t)l * 4 * 6 * 300, emb);
        aggregate<<<(N * 64 + 255) / 256, 256, 0, stream>>>(
            buf_y, emb, offs, vals, buf_agg, N);
        (void)hipMemsetAsync(stats, 0, 2 * DP * 4, stream);
        fused_mlp<<<MBF, 512, 0, stream>>>(
            buf_agg,
            w1t + (size_t)l * HP * DP, w2c + (size_t)l * DP * HP,
            b1 + (size_t)l * 600, b2 + (size_t)l * 300,
            buf_h, stats, stats + DP, N);
        bn_ss<<<1, DP, 0, stream>>>(stats, gamma + (size_t)l * 300, beta + (size_t)l * 300, scale, shift, N);
        if (l < L - 1)
            bn_apply<<<N, DP, 0, stream>>>(buf_h, scale, shift, buf_y);
    }
    finalize<<<N, DP, 0, stream>>>(buf_h, scale, shift, out);
}